// Round 11
// baseline (149.021 us; speedup 1.0000x reference)
//
#include <hip/hip_runtime.h>
#include <math.h>

#define BATCH  4
#define SEQL   4096
#define DMODEL 1024
#define NSTATE 64
#define LN_EPS 1e-5f
#define TB     16          // time rows processed per iteration

typedef unsigned short u16;

__device__ __forceinline__ u16 f2bf(float x) {
    unsigned int b = __float_as_uint(x);
    b += 0x7FFF + ((b >> 16) & 1);       // round-to-nearest-even
    return (u16)(b >> 16);
}
__device__ __forceinline__ float bf2f(u16 h) {
    return __uint_as_float(((unsigned int)h) << 16);
}

// ---------------------------------------------------------------------------
// k_local: block = (b, d-tile 64, chunk j). 4 waves; wave w owns states
// n in [16w, 16w+16); lane = d. Local scan, ZERO init; bf16 finals
// f[b][j][n][d]. min-waves=2 -> 256-VGPR budget so ur/r/s stay in registers.
// ---------------------------------------------------------------------------
__global__ __launch_bounds__(256, 2) void k_local(const float* __restrict__ u,
                                                  const float* __restrict__ A_log,
                                                  const float* __restrict__ delta,
                                                  u16* __restrict__ f,
                                                  int NCH, int TCH) {
    __shared__ float r_lds[NSTATE];
    const int tid = threadIdx.x;
    const int w = tid >> 6, l = tid & 63;
    const int b   = blockIdx.x / (16 * NCH);
    const int rem = blockIdx.x % (16 * NCH);
    const int dt  = rem / NCH;
    const int j   = rem % NCH;
    const int n0  = w << 4;
    const int d   = (dt << 6) | l;

    if (tid < NSTATE) r_lds[tid] = expf(delta[0] * -expf(A_log[tid]));
    __syncthreads();

    float r_[16];
#pragma unroll
    for (int q = 0; q < 4; ++q)
        *(float4*)&r_[q * 4] = *(const float4*)&r_lds[n0 + q * 4];

    float s_[16];
#pragma unroll
    for (int i = 0; i < 16; ++i) s_[i] = 0.f;

    const float* ub = u + ((size_t)b * SEQL + (size_t)j * TCH) * DMODEL + d;
    for (int tb = 0; tb < TCH / TB; ++tb) {
        float ur[TB];
#pragma unroll
        for (int t = 0; t < TB; ++t)
            ur[t] = ub[(size_t)(tb * TB + t) * DMODEL];
#pragma unroll
        for (int q = 0; q < 4; ++q) {
            float s0 = s_[q*4], s1 = s_[q*4+1], s2 = s_[q*4+2], s3 = s_[q*4+3];
            const float r0 = r_[q*4], r1 = r_[q*4+1], r2 = r_[q*4+2], r3 = r_[q*4+3];
#pragma unroll
            for (int t = 0; t < TB; ++t) {
                const float ut = ur[t];
                s0 = fmaf(r0, s0, ut);
                s1 = fmaf(r1, s1, ut);
                s2 = fmaf(r2, s2, ut);
                s3 = fmaf(r3, s3, ut);
            }
            s_[q*4] = s0; s_[q*4+1] = s1; s_[q*4+2] = s2; s_[q*4+3] = s3;
        }
    }
    u16* fb = f + (((size_t)b * NCH + j) * NSTATE + n0) * DMODEL + d;
#pragma unroll
    for (int i = 0; i < 16; ++i) fb[(size_t)i * DMODEL] = f2bf(s_[i]);
}

// ---------------------------------------------------------------------------
// k_pass2: in-place boundary scan (bf16). f[b][j][n][d] (local finals) ->
// I[b][j][n][d] = state ENTERING chunk j. One thread per (b,n,d).
// ---------------------------------------------------------------------------
__global__ __launch_bounds__(256) void k_pass2(const float* __restrict__ A_log,
                                               const float* __restrict__ delta,
                                               u16* __restrict__ f,
                                               int NCH, int TCH) {
    const int tid = blockIdx.x * 256 + threadIdx.x;  // over B*N*D
    const int d = tid & (DMODEL - 1);
    const int n = (tid >> 10) & (NSTATE - 1);
    const int b = tid >> 16;
    const float A  = -expf(A_log[n]);
    const float rT = expf((float)TCH * delta[0] * A);
    float I = 0.f;
    u16* p = f + ((size_t)b * NCH * NSTATE + n) * DMODEL + d;
    const size_t stride = (size_t)NSTATE * DMODEL;
    for (int j = 0; j < NCH; ++j) {
        float tmp = bf2f(p[(size_t)j * stride]);
        p[(size_t)j * stride] = f2bf(I);
        I = fmaf(rT, I, tmp);
    }
}

// ---------------------------------------------------------------------------
// k_replay: block = (b, d-tile 64, chunk j); wave w owns n in [16w,16w+16),
// lane = d. Replays scan with initial state I; emits
//   z[t,d] = fal[d]*( sum_n C[d,n] s[n,t,d] + D[d] u[t,d] ) + reward[d]*(t==0)
// fal pre-folded into c_ and the D-term. Partials reduced via LDS per TB.
// min-waves=2 -> 256-VGPR budget so ur/zr/s/r/c all stay in registers.
// ---------------------------------------------------------------------------
__global__ __launch_bounds__(256, 2) void k_replay(const float* __restrict__ u,
                                                   const float* __restrict__ A_log,
                                                   const float* __restrict__ C,
                                                   const float* __restrict__ Dvec,
                                                   const float* __restrict__ delta,
                                                   const u16* __restrict__ I,
                                                   const float* __restrict__ fal,
                                                   const float* __restrict__ rw,
                                                   float* __restrict__ z,
                                                   int NCH, int TCH) {
    __shared__ float r_lds[NSTATE];
    __shared__ float part[4][TB][64];                // 16 KB
    const int tid = threadIdx.x;
    const int w = tid >> 6, l = tid & 63;
    const int b   = blockIdx.x / (16 * NCH);
    const int rem = blockIdx.x % (16 * NCH);
    const int dt  = rem / NCH;
    const int j   = rem % NCH;
    const int n0  = w << 4;
    const int d   = (dt << 6) | l;

    if (tid < NSTATE) r_lds[tid] = expf(delta[0] * -expf(A_log[tid]));
    __syncthreads();

    const float fad = fal[d];
    float r_[16], c_[16], s_[16];
#pragma unroll
    for (int q = 0; q < 4; ++q)
        *(float4*)&r_[q * 4] = *(const float4*)&r_lds[n0 + q * 4];
#pragma unroll
    for (int i = 0; i < 16; ++i)
        c_[i] = fad * C[(size_t)d * NSTATE + n0 + i];  // L2-resident, once
    const u16* Ib = I + (((size_t)b * NCH + j) * NSTATE + n0) * DMODEL + d;
#pragma unroll
    for (int i = 0; i < 16; ++i) s_[i] = bf2f(Ib[(size_t)i * DMODEL]);

    const float Ddf = Dvec[d] * fad;
    const float rwd = rw[d];
    const float* ub = u + ((size_t)b * SEQL + (size_t)j * TCH) * DMODEL + d;
    float*       zb = z + ((size_t)b * SEQL + (size_t)j * TCH) * DMODEL + d;

    for (int tb = 0; tb < TCH / TB; ++tb) {
        float ur[TB], zr[TB];
#pragma unroll
        for (int t = 0; t < TB; ++t) {
            ur[t] = ub[(size_t)(tb * TB + t) * DMODEL];
            zr[t] = 0.f;
        }
#pragma unroll
        for (int q = 0; q < 4; ++q) {
            float s0 = s_[q*4], s1 = s_[q*4+1], s2 = s_[q*4+2], s3 = s_[q*4+3];
            const float r0 = r_[q*4], r1 = r_[q*4+1], r2 = r_[q*4+2], r3 = r_[q*4+3];
            const float c0 = c_[q*4], c1 = c_[q*4+1], c2 = c_[q*4+2], c3 = c_[q*4+3];
#pragma unroll
            for (int t = 0; t < TB; ++t) {
                const float ut = ur[t];
                s0 = fmaf(r0, s0, ut);
                s1 = fmaf(r1, s1, ut);
                s2 = fmaf(r2, s2, ut);
                s3 = fmaf(r3, s3, ut);
                float a = fmaf(c0, s0, zr[t]);
                a = fmaf(c1, s1, a);
                a = fmaf(c2, s2, a);
                zr[t] = fmaf(c3, s3, a);
            }
            s_[q*4] = s0; s_[q*4+1] = s1; s_[q*4+2] = s2; s_[q*4+3] = s3;
        }
        // wave 0 adds the (fal-folded) D-term before the cross-wave reduce
        if (w == 0) {
#pragma unroll
            for (int t = 0; t < TB; ++t) zr[t] = fmaf(Ddf, ur[t], zr[t]);
        }
#pragma unroll
        for (int t = 0; t < TB; ++t) part[w][t][l] = zr[t];
        __syncthreads();
        // wave w finalizes rows [4w, 4w+4)
#pragma unroll
        for (int k = 0; k < 4; ++k) {
            const int t = (w << 2) | k;
            float v = (part[0][t][l] + part[1][t][l]) +
                      (part[2][t][l] + part[3][t][l]);
            if (j == 0 && tb == 0 && t == 0) v += rwd;
            zb[(size_t)(tb * TB + t) * DMODEL] = v;
        }
        __syncthreads();                              // part reuse guard
    }
}

// ---------------------------------------------------------------------------
// k_ln: pure in-place LayerNorm over d. One block per (b,t) row.
// ---------------------------------------------------------------------------
__global__ __launch_bounds__(256) void k_ln(float* __restrict__ y,
                                            const float* __restrict__ gamma,
                                            const float* __restrict__ beta) {
    const int tid = threadIdx.x;
    float4* row = (float4*)(y + (size_t)blockIdx.x * DMODEL);
    float4 v = row[tid];
    float sum = v.x + v.y + v.z + v.w;
    float sq  = v.x*v.x + v.y*v.y + v.z*v.z + v.w*v.w;
#pragma unroll
    for (int off = 32; off > 0; off >>= 1) {
        sum += __shfl_down(sum, off, 64);
        sq  += __shfl_down(sq,  off, 64);
    }
    __shared__ float red[8];
    const int wave = tid >> 6, lane = tid & 63;
    if (lane == 0) { red[wave] = sum; red[4 + wave] = sq; }
    __syncthreads();
    sum = red[0] + red[1] + red[2] + red[3];
    sq  = red[4] + red[5] + red[6] + red[7];
    const float mean = sum * (1.f / DMODEL);
    const float var  = sq * (1.f / DMODEL) - mean * mean;
    const float inv  = 1.f / sqrtf(var + LN_EPS);
    const float4 g  = ((const float4*)gamma)[tid];
    const float4 bb = ((const float4*)beta)[tid];
    float4 o;
    o.x = (v.x - mean) * inv * g.x + bb.x;
    o.y = (v.y - mean) * inv * g.y + bb.y;
    o.z = (v.z - mean) * inv * g.z + bb.z;
    o.w = (v.w - mean) * inv * g.w + bb.w;
    row[tid] = o;
}

// ---------------------------------------------------------------------------
// k_state: final_state[b,n] = ((exp(dmean*A_n)-1)/A_safe_n) *
//                             sum_d B[n,d] * u[b, L-1, d]
// ---------------------------------------------------------------------------
__global__ __launch_bounds__(256) void k_state(const float* __restrict__ u,
                                               const float* __restrict__ A_log,
                                               const float* __restrict__ B,
                                               const float* __restrict__ delta,
                                               float* __restrict__ out) {
    const int n = blockIdx.x & 63;
    const int b = blockIdx.x >> 6;
    const int tid = threadIdx.x;
    const float* ul = u + ((size_t)b * SEQL + (SEQL - 1)) * DMODEL;
    const float* Bn = B + (size_t)n * DMODEL;
    float dot = 0.f, dsum = 0.f;
    for (int dd = tid; dd < DMODEL; dd += 256) {
        dot = fmaf(Bn[dd], ul[dd], dot);
        dsum += delta[dd];
    }
#pragma unroll
    for (int off = 32; off > 0; off >>= 1) {
        dot  += __shfl_down(dot,  off, 64);
        dsum += __shfl_down(dsum, off, 64);
    }
    __shared__ float red[8];
    const int wave = tid >> 6, lane = tid & 63;
    if (lane == 0) { red[wave] = dot; red[4 + wave] = dsum; }
    __syncthreads();
    if (tid == 0) {
        dot  = red[0] + red[1] + red[2] + red[3];
        dsum = red[4] + red[5] + red[6] + red[7];
        const float dmean = dsum * (1.f / DMODEL);
        const float A = -expf(A_log[n]);
        const float Abar = expf(dmean * A);
        const float Asafe = A + (A >= 0.f ? 1e-8f : -1e-8f);
        out[blockIdx.x] = ((Abar - 1.f) / Asafe) * dot;
    }
}

extern "C" void kernel_launch(void* const* d_in, const int* in_sizes, int n_in,
                              void* d_out, int out_size, void* d_ws, size_t ws_size,
                              hipStream_t stream) {
    const float* u     = (const float*)d_in[0];
    const float* A_log = (const float*)d_in[1];
    const float* B     = (const float*)d_in[2];
    const float* C     = (const float*)d_in[3];
    const float* Dv    = (const float*)d_in[4];
    const float* delta = (const float*)d_in[5];
    const float* gamma = (const float*)d_in[6];
    const float* beta  = (const float*)d_in[7];
    const float* fal   = (const float*)d_in[8];
    const float* rw    = (const float*)d_in[9];

    float* y  = (float*)d_out;
    float* st = y + (size_t)BATCH * SEQL * DMODEL;
    u16* f    = (u16*)d_ws;

    int NCH = 32;
    while (NCH > 4 && (size_t)BATCH * NCH * NSTATE * DMODEL * sizeof(u16) > ws_size)
        NCH >>= 1;
    const int TCH = SEQL / NCH;
    const int nb = BATCH * 16 * NCH;

    hipLaunchKernelGGL(k_local, dim3(nb), dim3(256), 0, stream, u, A_log, delta, f, NCH, TCH);
    hipLaunchKernelGGL(k_pass2, dim3(BATCH * NSTATE * DMODEL / 256), dim3(256), 0, stream,
                       A_log, delta, f, NCH, TCH);
    hipLaunchKernelGGL(k_replay, dim3(nb), dim3(256), 0, stream,
                       u, A_log, C, Dv, delta, f, fal, rw, y, NCH, TCH);
    hipLaunchKernelGGL(k_ln, dim3(BATCH * SEQL), dim3(256), 0, stream, y, gamma, beta);
    hipLaunchKernelGGL(k_state, dim3(BATCH * NSTATE), dim3(256), 0, stream,
                       u, A_log, B, delta, st);
}

// Round 12
// 130.840 us; speedup vs baseline: 1.1390x; 1.1390x over previous
//
#include <hip/hip_runtime.h>
#include <math.h>

#define BATCH  4
#define SEQL   4096
#define DMODEL 1024
#define NSTATE 64
#define LN_EPS 1e-5f
#define TB     16          // time rows processed per iteration

typedef unsigned short u16;
typedef float f32x2 __attribute__((ext_vector_type(2)));

// Packed f32 FMA pair -> v_pk_fma_f32 on gfx90a+ (halves FMA issue count).
__device__ __forceinline__ f32x2 fma2(f32x2 a, f32x2 b, f32x2 c) {
#if __has_builtin(__builtin_elementwise_fma)
    return __builtin_elementwise_fma(a, b, c);
#else
    f32x2 d; d.x = fmaf(a.x, b.x, c.x); d.y = fmaf(a.y, b.y, c.y); return d;
#endif
}

__device__ __forceinline__ u16 f2bf(float x) {
    unsigned int b = __float_as_uint(x);
    b += 0x7FFF + ((b >> 16) & 1);       // round-to-nearest-even
    return (u16)(b >> 16);
}
__device__ __forceinline__ float bf2f(u16 h) {
    return __uint_as_float(((unsigned int)h) << 16);
}

// ---------------------------------------------------------------------------
// k_local: block = (b, d-tile 64, chunk j). 4 waves; wave w owns states
// n in [16w, 16w+16); lane = d. Local scan, ZERO init; bf16 finals
// f[b][j][n][d]. Packed-pair recurrence: 8 pk-FMA per t per thread.
// ---------------------------------------------------------------------------
__global__ __launch_bounds__(256) void k_local(const float* __restrict__ u,
                                               const float* __restrict__ A_log,
                                               const float* __restrict__ delta,
                                               u16* __restrict__ f,
                                               int NCH, int TCH) {
    __shared__ float r_lds[NSTATE];
    const int tid = threadIdx.x;
    const int w = tid >> 6, l = tid & 63;
    const int b   = blockIdx.x / (16 * NCH);
    const int rem = blockIdx.x % (16 * NCH);
    const int dt  = rem / NCH;
    const int j   = rem % NCH;
    const int n0  = w << 4;
    const int d   = (dt << 6) | l;

    if (tid < NSTATE) r_lds[tid] = expf(delta[0] * -expf(A_log[tid]));
    __syncthreads();

    f32x2 r2[8], s2[8];
#pragma unroll
    for (int p = 0; p < 8; ++p) {
        r2[p] = *(const f32x2*)&r_lds[n0 + 2 * p];
        s2[p] = (f32x2)(0.f, 0.f);
    }

    const float* ub = u + ((size_t)b * SEQL + (size_t)j * TCH) * DMODEL + d;
    for (int tb = 0; tb < TCH / TB; ++tb) {
        float ur[TB];
#pragma unroll
        for (int t = 0; t < TB; ++t)
            ur[t] = ub[(size_t)(tb * TB + t) * DMODEL];
#pragma unroll
        for (int q = 0; q < 4; ++q) {
            f32x2 sa = s2[2*q], sb = s2[2*q+1];
            const f32x2 ra = r2[2*q], rb = r2[2*q+1];
#pragma unroll
            for (int t = 0; t < TB; ++t) {
                f32x2 u2; u2.x = ur[t]; u2.y = ur[t];
                sa = fma2(ra, sa, u2);
                sb = fma2(rb, sb, u2);
            }
            s2[2*q] = sa; s2[2*q+1] = sb;
        }
    }
    u16* fb = f + (((size_t)b * NCH + j) * NSTATE + n0) * DMODEL + d;
#pragma unroll
    for (int p = 0; p < 8; ++p) {
        fb[(size_t)(2*p)     * DMODEL] = f2bf(s2[p].x);
        fb[(size_t)(2*p + 1) * DMODEL] = f2bf(s2[p].y);
    }
}

// ---------------------------------------------------------------------------
// k_pass2: in-place boundary scan (bf16). f[b][j][n][d] (local finals) ->
// I[b][j][n][d] = state ENTERING chunk j. One thread per (b,n,d).
// ---------------------------------------------------------------------------
__global__ __launch_bounds__(256) void k_pass2(const float* __restrict__ A_log,
                                               const float* __restrict__ delta,
                                               u16* __restrict__ f,
                                               int NCH, int TCH) {
    const int tid = blockIdx.x * 256 + threadIdx.x;  // over B*N*D
    const int d = tid & (DMODEL - 1);
    const int n = (tid >> 10) & (NSTATE - 1);
    const int b = tid >> 16;
    const float A  = -expf(A_log[n]);
    const float rT = expf((float)TCH * delta[0] * A);
    float I = 0.f;
    u16* p = f + ((size_t)b * NCH * NSTATE + n) * DMODEL + d;
    const size_t stride = (size_t)NSTATE * DMODEL;
    for (int j = 0; j < NCH; ++j) {
        float tmp = bf2f(p[(size_t)j * stride]);
        p[(size_t)j * stride] = f2bf(I);
        I = fmaf(rT, I, tmp);
    }
}

// ---------------------------------------------------------------------------
// k_replay: block = (b, d-tile 64, chunk j); wave w owns n in [16w,16w+16),
// lane = d. Replays scan with initial state I (bf16); emits
//   z[t,d] = fal[d]*( sum_n C[d,n] s[n,t,d] + D[d] u[t,d] ) + reward[d]*(t==0)
// fal folded into c_/D. Packed pairs: 16 pk-FMA per t per thread.
// Cross-wave partials reduced via LDS once per TB rows.
// ---------------------------------------------------------------------------
__global__ __launch_bounds__(256) void k_replay(const float* __restrict__ u,
                                                const float* __restrict__ A_log,
                                                const float* __restrict__ C,
                                                const float* __restrict__ Dvec,
                                                const float* __restrict__ delta,
                                                const u16* __restrict__ I,
                                                const float* __restrict__ fal,
                                                const float* __restrict__ rw,
                                                float* __restrict__ z,
                                                int NCH, int TCH) {
    __shared__ float r_lds[NSTATE];
    __shared__ float part[4][TB][64];                // 16 KB
    const int tid = threadIdx.x;
    const int w = tid >> 6, l = tid & 63;
    const int b   = blockIdx.x / (16 * NCH);
    const int rem = blockIdx.x % (16 * NCH);
    const int dt  = rem / NCH;
    const int j   = rem % NCH;
    const int n0  = w << 4;
    const int d   = (dt << 6) | l;

    if (tid < NSTATE) r_lds[tid] = expf(delta[0] * -expf(A_log[tid]));
    __syncthreads();

    const float fad = fal[d];
    f32x2 r2[8], c2[8], s2[8];
#pragma unroll
    for (int p = 0; p < 8; ++p)
        r2[p] = *(const f32x2*)&r_lds[n0 + 2 * p];
#pragma unroll
    for (int p = 0; p < 8; ++p) {
        c2[p].x = fad * C[(size_t)d * NSTATE + n0 + 2*p];
        c2[p].y = fad * C[(size_t)d * NSTATE + n0 + 2*p + 1];
    }
    const u16* Ib = I + (((size_t)b * NCH + j) * NSTATE + n0) * DMODEL + d;
#pragma unroll
    for (int p = 0; p < 8; ++p) {
        s2[p].x = bf2f(Ib[(size_t)(2*p)     * DMODEL]);
        s2[p].y = bf2f(Ib[(size_t)(2*p + 1) * DMODEL]);
    }

    const float Ddf = Dvec[d] * fad;
    const float rwd = rw[d];
    const float* ub = u + ((size_t)b * SEQL + (size_t)j * TCH) * DMODEL + d;
    float*       zb = z + ((size_t)b * SEQL + (size_t)j * TCH) * DMODEL + d;

    for (int tb = 0; tb < TCH / TB; ++tb) {
        float ur[TB];
        f32x2 zr2[TB];
#pragma unroll
        for (int t = 0; t < TB; ++t) {
            ur[t] = ub[(size_t)(tb * TB + t) * DMODEL];
            zr2[t] = (f32x2)(0.f, 0.f);
        }
#pragma unroll
        for (int q = 0; q < 4; ++q) {
            f32x2 sa = s2[2*q], sb = s2[2*q+1];
            const f32x2 ra = r2[2*q], rb = r2[2*q+1];
            const f32x2 ca = c2[2*q], cb = c2[2*q+1];
#pragma unroll
            for (int t = 0; t < TB; ++t) {
                f32x2 u2; u2.x = ur[t]; u2.y = ur[t];
                sa = fma2(ra, sa, u2);
                sb = fma2(rb, sb, u2);
                zr2[t] = fma2(ca, sa, zr2[t]);
                zr2[t] = fma2(cb, sb, zr2[t]);
            }
            s2[2*q] = sa; s2[2*q+1] = sb;
        }
        // fold pair-halves; wave 0 adds the (fal-folded) D-term
#pragma unroll
        for (int t = 0; t < TB; ++t) {
            float v = zr2[t].x + zr2[t].y;
            if (w == 0) v = fmaf(Ddf, ur[t], v);
            part[w][t][l] = v;
        }
        __syncthreads();
        // wave w finalizes rows [4w, 4w+4)
#pragma unroll
        for (int k = 0; k < 4; ++k) {
            const int t = (w << 2) | k;
            float v = (part[0][t][l] + part[1][t][l]) +
                      (part[2][t][l] + part[3][t][l]);
            if (j == 0 && tb == 0 && t == 0) v += rwd;
            zb[(size_t)(tb * TB + t) * DMODEL] = v;
        }
        __syncthreads();                              // part reuse guard
    }
}

// ---------------------------------------------------------------------------
// k_ln: pure in-place LayerNorm over d. One block per (b,t) row.
// ---------------------------------------------------------------------------
__global__ __launch_bounds__(256) void k_ln(float* __restrict__ y,
                                            const float* __restrict__ gamma,
                                            const float* __restrict__ beta) {
    const int tid = threadIdx.x;
    float4* row = (float4*)(y + (size_t)blockIdx.x * DMODEL);
    float4 v = row[tid];
    float sum = v.x + v.y + v.z + v.w;
    float sq  = v.x*v.x + v.y*v.y + v.z*v.z + v.w*v.w;
#pragma unroll
    for (int off = 32; off > 0; off >>= 1) {
        sum += __shfl_down(sum, off, 64);
        sq  += __shfl_down(sq,  off, 64);
    }
    __shared__ float red[8];
    const int wave = tid >> 6, lane = tid & 63;
    if (lane == 0) { red[wave] = sum; red[4 + wave] = sq; }
    __syncthreads();
    sum = red[0] + red[1] + red[2] + red[3];
    sq  = red[4] + red[5] + red[6] + red[7];
    const float mean = sum * (1.f / DMODEL);
    const float var  = sq * (1.f / DMODEL) - mean * mean;
    const float inv  = 1.f / sqrtf(var + LN_EPS);
    const float4 g  = ((const float4*)gamma)[tid];
    const float4 bb = ((const float4*)beta)[tid];
    float4 o;
    o.x = (v.x - mean) * inv * g.x + bb.x;
    o.y = (v.y - mean) * inv * g.y + bb.y;
    o.z = (v.z - mean) * inv * g.z + bb.z;
    o.w = (v.w - mean) * inv * g.w + bb.w;
    row[tid] = o;
}

// ---------------------------------------------------------------------------
// k_state: final_state[b,n] = ((exp(dmean*A_n)-1)/A_safe_n) *
//                             sum_d B[n,d] * u[b, L-1, d]
// ---------------------------------------------------------------------------
__global__ __launch_bounds__(256) void k_state(const float* __restrict__ u,
                                               const float* __restrict__ A_log,
                                               const float* __restrict__ B,
                                               const float* __restrict__ delta,
                                               float* __restrict__ out) {
    const int n = blockIdx.x & 63;
    const int b = blockIdx.x >> 6;
    const int tid = threadIdx.x;
    const float* ul = u + ((size_t)b * SEQL + (SEQL - 1)) * DMODEL;
    const float* Bn = B + (size_t)n * DMODEL;
    float dot = 0.f, dsum = 0.f;
    for (int dd = tid; dd < DMODEL; dd += 256) {
        dot = fmaf(Bn[dd], ul[dd], dot);
        dsum += delta[dd];
    }
#pragma unroll
    for (int off = 32; off > 0; off >>= 1) {
        dot  += __shfl_down(dot,  off, 64);
        dsum += __shfl_down(dsum, off, 64);
    }
    __shared__ float red[8];
    const int wave = tid >> 6, lane = tid & 63;
    if (lane == 0) { red[wave] = dot; red[4 + wave] = dsum; }
    __syncthreads();
    if (tid == 0) {
        dot  = red[0] + red[1] + red[2] + red[3];
        dsum = red[4] + red[5] + red[6] + red[7];
        const float dmean = dsum * (1.f / DMODEL);
        const float A = -expf(A_log[n]);
        const float Abar = expf(dmean * A);
        const float Asafe = A + (A >= 0.f ? 1e-8f : -1e-8f);
        out[blockIdx.x] = ((Abar - 1.f) / Asafe) * dot;
    }
}

extern "C" void kernel_launch(void* const* d_in, const int* in_sizes, int n_in,
                              void* d_out, int out_size, void* d_ws, size_t ws_size,
                              hipStream_t stream) {
    const float* u     = (const float*)d_in[0];
    const float* A_log = (const float*)d_in[1];
    const float* B     = (const float*)d_in[2];
    const float* C     = (const float*)d_in[3];
    const float* Dv    = (const float*)d_in[4];
    const float* delta = (const float*)d_in[5];
    const float* gamma = (const float*)d_in[6];
    const float* beta  = (const float*)d_in[7];
    const float* fal   = (const float*)d_in[8];
    const float* rw    = (const float*)d_in[9];

    float* y  = (float*)d_out;
    float* st = y + (size_t)BATCH * SEQL * DMODEL;
    u16* f    = (u16*)d_ws;

    int NCH = 32;
    while (NCH > 4 && (size_t)BATCH * NCH * NSTATE * DMODEL * sizeof(u16) > ws_size)
        NCH >>= 1;
    const int TCH = SEQL / NCH;
    const int nb = BATCH * 16 * NCH;

    hipLaunchKernelGGL(k_local, dim3(nb), dim3(256), 0, stream, u, A_log, delta, f, NCH, TCH);
    hipLaunchKernelGGL(k_pass2, dim3(BATCH * NSTATE * DMODEL / 256), dim3(256), 0, stream,
                       A_log, delta, f, NCH, TCH);
    hipLaunchKernelGGL(k_replay, dim3(nb), dim3(256), 0, stream,
                       u, A_log, C, Dv, delta, f, fal, rw, y, NCH, TCH);
    hipLaunchKernelGGL(k_ln, dim3(BATCH * SEQL), dim3(256), 0, stream, y, gamma, beta);
    hipLaunchKernelGGL(k_state, dim3(BATCH * NSTATE), dim3(256), 0, stream,
                       u, A_log, B, delta, st);
}

// Round 13
// 124.075 us; speedup vs baseline: 1.2011x; 1.0545x over previous
//
#include <hip/hip_runtime.h>
#include <math.h>

#define BATCH  4
#define SEQL   4096
#define DMODEL 1024
#define NSTATE 64
#define LN_EPS 1e-5f
#define TB     16          // time rows processed per iteration

typedef unsigned short u16;
typedef float f32x2 __attribute__((ext_vector_type(2)));

// Packed f32 FMA pair -> v_pk_fma_f32 (halves FMA issue count).
__device__ __forceinline__ f32x2 fma2(f32x2 a, f32x2 b, f32x2 c) {
#if __has_builtin(__builtin_elementwise_fma)
    return __builtin_elementwise_fma(a, b, c);
#else
    f32x2 d; d.x = fmaf(a.x, b.x, c.x); d.y = fmaf(a.y, b.y, c.y); return d;
#endif
}

__device__ __forceinline__ u16 f2bf(float x) {
    unsigned int b = __float_as_uint(x);
    b += 0x7FFF + ((b >> 16) & 1);       // round-to-nearest-even
    return (u16)(b >> 16);
}
__device__ __forceinline__ float bf2f(u16 h) {
    return __uint_as_float(((unsigned int)h) << 16);
}

// ---------------------------------------------------------------------------
// k_local: block = (b, d-tile 64, chunk j). 4 waves; wave w owns states
// n in [16w, 16w+16); lane = d. Local scan, ZERO init; bf16 finals
// f[b][j][n][d]. Packed-pair recurrence: 8 pk-FMA per t per thread.
// ---------------------------------------------------------------------------
__global__ __launch_bounds__(256) void k_local(const float* __restrict__ u,
                                               const float* __restrict__ A_log,
                                               const float* __restrict__ delta,
                                               u16* __restrict__ f,
                                               int NCH, int TCH) {
    __shared__ float r_lds[NSTATE];
    const int tid = threadIdx.x;
    const int w = tid >> 6, l = tid & 63;
    const int b   = blockIdx.x / (16 * NCH);
    const int rem = blockIdx.x % (16 * NCH);
    const int dt  = rem / NCH;
    const int j   = rem % NCH;
    const int n0  = w << 4;
    const int d   = (dt << 6) | l;

    if (tid < NSTATE) r_lds[tid] = expf(delta[0] * -expf(A_log[tid]));
    __syncthreads();

    f32x2 r2[8], s2[8];
#pragma unroll
    for (int p = 0; p < 8; ++p) {
        r2[p] = *(const f32x2*)&r_lds[n0 + 2 * p];
        s2[p] = (f32x2)(0.f, 0.f);
    }

    const float* ub = u + ((size_t)b * SEQL + (size_t)j * TCH) * DMODEL + d;
    for (int tb = 0; tb < TCH / TB; ++tb) {
        float ur[TB];
#pragma unroll
        for (int t = 0; t < TB; ++t)
            ur[t] = ub[(size_t)(tb * TB + t) * DMODEL];
#pragma unroll
        for (int q = 0; q < 4; ++q) {
            f32x2 sa = s2[2*q], sb = s2[2*q+1];
            const f32x2 ra = r2[2*q], rb = r2[2*q+1];
#pragma unroll
            for (int t = 0; t < TB; ++t) {
                f32x2 u2; u2.x = ur[t]; u2.y = ur[t];
                sa = fma2(ra, sa, u2);
                sb = fma2(rb, sb, u2);
            }
            s2[2*q] = sa; s2[2*q+1] = sb;
        }
    }
    u16* fb = f + (((size_t)b * NCH + j) * NSTATE + n0) * DMODEL + d;
#pragma unroll
    for (int p = 0; p < 8; ++p) {
        fb[(size_t)(2*p)     * DMODEL] = f2bf(s2[p].x);
        fb[(size_t)(2*p + 1) * DMODEL] = f2bf(s2[p].y);
    }
}

// ---------------------------------------------------------------------------
// k_pass2: in-place boundary scan (bf16). f[b][j][n][d] (local finals) ->
// I[b][j][n][d] = state ENTERING chunk j. One thread per (b,n,d).
// ---------------------------------------------------------------------------
__global__ __launch_bounds__(256) void k_pass2(const float* __restrict__ A_log,
                                               const float* __restrict__ delta,
                                               u16* __restrict__ f,
                                               int NCH, int TCH) {
    const int tid = blockIdx.x * 256 + threadIdx.x;  // over B*N*D
    const int d = tid & (DMODEL - 1);
    const int n = (tid >> 10) & (NSTATE - 1);
    const int b = tid >> 16;
    const float A  = -expf(A_log[n]);
    const float rT = expf((float)TCH * delta[0] * A);
    float I = 0.f;
    u16* p = f + ((size_t)b * NCH * NSTATE + n) * DMODEL + d;
    const size_t stride = (size_t)NSTATE * DMODEL;
    for (int j = 0; j < NCH; ++j) {
        float tmp = bf2f(p[(size_t)j * stride]);
        p[(size_t)j * stride] = f2bf(I);
        I = fmaf(rT, I, tmp);
    }
}

// ---------------------------------------------------------------------------
// k_replay<ZBF16>: block = (b, d-tile 64, chunk j); wave w owns n in
// [16w,16w+16), lane = d. Replays scan with initial state I (bf16); emits
//   z[t,d] = fal[d]*( sum_n C[d,n] s[n,t,d] + D[d] u[t,d] ) + reward[d]*(t==0)
// fal folded into c_/D. Packed pairs. Cross-wave partials via double-buffered
// LDS (one barrier per TB tile). z stored bf16 (ws) or f32 (fallback).
// ---------------------------------------------------------------------------
template <bool ZBF16>
__global__ __launch_bounds__(256) void k_replay(const float* __restrict__ u,
                                                const float* __restrict__ A_log,
                                                const float* __restrict__ C,
                                                const float* __restrict__ Dvec,
                                                const float* __restrict__ delta,
                                                const u16* __restrict__ I,
                                                const float* __restrict__ fal,
                                                const float* __restrict__ rw,
                                                void* __restrict__ zout,
                                                int NCH, int TCH) {
    __shared__ float r_lds[NSTATE];
    __shared__ float part[2][4][TB][64];             // 32 KB, double-buffered
    const int tid = threadIdx.x;
    const int w = tid >> 6, l = tid & 63;
    const int b   = blockIdx.x / (16 * NCH);
    const int rem = blockIdx.x % (16 * NCH);
    const int dt  = rem / NCH;
    const int j   = rem % NCH;
    const int n0  = w << 4;
    const int d   = (dt << 6) | l;

    if (tid < NSTATE) r_lds[tid] = expf(delta[0] * -expf(A_log[tid]));
    __syncthreads();

    const float fad = fal[d];
    f32x2 r2[8], c2[8], s2[8];
#pragma unroll
    for (int p = 0; p < 8; ++p)
        r2[p] = *(const f32x2*)&r_lds[n0 + 2 * p];
#pragma unroll
    for (int p = 0; p < 8; ++p) {
        c2[p].x = fad * C[(size_t)d * NSTATE + n0 + 2*p];
        c2[p].y = fad * C[(size_t)d * NSTATE + n0 + 2*p + 1];
    }
    const u16* Ib = I + (((size_t)b * NCH + j) * NSTATE + n0) * DMODEL + d;
#pragma unroll
    for (int p = 0; p < 8; ++p) {
        s2[p].x = bf2f(Ib[(size_t)(2*p)     * DMODEL]);
        s2[p].y = bf2f(Ib[(size_t)(2*p + 1) * DMODEL]);
    }

    const float Ddf = Dvec[d] * fad;
    const float rwd = rw[d];
    const float* ub = u + ((size_t)b * SEQL + (size_t)j * TCH) * DMODEL + d;
    const size_t zoff = ((size_t)b * SEQL + (size_t)j * TCH) * DMODEL + d;
    u16*   zb16 = (u16*)zout + zoff;
    float* zb32 = (float*)zout + zoff;

    for (int tb = 0; tb < TCH / TB; ++tb) {
        const int pb = tb & 1;
        float ur[TB];
        f32x2 zr2[TB];
#pragma unroll
        for (int t = 0; t < TB; ++t) {
            ur[t] = ub[(size_t)(tb * TB + t) * DMODEL];
            zr2[t] = (f32x2)(0.f, 0.f);
        }
#pragma unroll
        for (int q = 0; q < 4; ++q) {
            f32x2 sa = s2[2*q], sb = s2[2*q+1];
            const f32x2 ra = r2[2*q], rb = r2[2*q+1];
            const f32x2 ca = c2[2*q], cb = c2[2*q+1];
#pragma unroll
            for (int t = 0; t < TB; ++t) {
                f32x2 u2; u2.x = ur[t]; u2.y = ur[t];
                sa = fma2(ra, sa, u2);
                sb = fma2(rb, sb, u2);
                zr2[t] = fma2(ca, sa, zr2[t]);
                zr2[t] = fma2(cb, sb, zr2[t]);
            }
            s2[2*q] = sa; s2[2*q+1] = sb;
        }
#pragma unroll
        for (int t = 0; t < TB; ++t) {
            float v = zr2[t].x + zr2[t].y;
            if (w == 0) v = fmaf(Ddf, ur[t], v);     // fal-folded D-term, once
            part[pb][w][t][l] = v;
        }
        __syncthreads();
        // wave w finalizes rows [4w, 4w+4); no trailing barrier (dbuf).
#pragma unroll
        for (int k = 0; k < 4; ++k) {
            const int t = (w << 2) | k;
            float v = (part[pb][0][t][l] + part[pb][1][t][l]) +
                      (part[pb][2][t][l] + part[pb][3][t][l]);
            if (j == 0 && tb == 0 && t == 0) v += rwd;
            if (ZBF16) zb16[(size_t)(tb * TB + t) * DMODEL] = f2bf(v);
            else       zb32[(size_t)(tb * TB + t) * DMODEL] = v;
        }
    }
}

// ---------------------------------------------------------------------------
// k_ln<ZBF16>: LayerNorm over d. Reads z (bf16 ws or f32), writes f32 y.
// One block per (b,t) row, 4 channels per thread.
// ---------------------------------------------------------------------------
template <bool ZBF16>
__global__ __launch_bounds__(256) void k_ln(const void* __restrict__ zin,
                                            float* __restrict__ y,
                                            const float* __restrict__ gamma,
                                            const float* __restrict__ beta) {
    const int tid = threadIdx.x;
    float4 v;
    if (ZBF16) {
        const ushort4 h = ((const ushort4*)((const u16*)zin + (size_t)blockIdx.x * DMODEL))[tid];
        v.x = bf2f(h.x); v.y = bf2f(h.y); v.z = bf2f(h.z); v.w = bf2f(h.w);
    } else {
        v = ((const float4*)((const float*)zin + (size_t)blockIdx.x * DMODEL))[tid];
    }
    float sum = v.x + v.y + v.z + v.w;
    float sq  = v.x*v.x + v.y*v.y + v.z*v.z + v.w*v.w;
#pragma unroll
    for (int off = 32; off > 0; off >>= 1) {
        sum += __shfl_down(sum, off, 64);
        sq  += __shfl_down(sq,  off, 64);
    }
    __shared__ float red[8];
    const int wave = tid >> 6, lane = tid & 63;
    if (lane == 0) { red[wave] = sum; red[4 + wave] = sq; }
    __syncthreads();
    sum = red[0] + red[1] + red[2] + red[3];
    sq  = red[4] + red[5] + red[6] + red[7];
    const float mean = sum * (1.f / DMODEL);
    const float var  = sq * (1.f / DMODEL) - mean * mean;
    const float inv  = 1.f / sqrtf(var + LN_EPS);
    const float4 g  = ((const float4*)gamma)[tid];
    const float4 bb = ((const float4*)beta)[tid];
    float4 o;
    o.x = (v.x - mean) * inv * g.x + bb.x;
    o.y = (v.y - mean) * inv * g.y + bb.y;
    o.z = (v.z - mean) * inv * g.z + bb.z;
    o.w = (v.w - mean) * inv * g.w + bb.w;
    ((float4*)(y + (size_t)blockIdx.x * DMODEL))[tid] = o;
}

// ---------------------------------------------------------------------------
// k_state: final_state[b,n] = ((exp(dmean*A_n)-1)/A_safe_n) *
//                             sum_d B[n,d] * u[b, L-1, d]
// ---------------------------------------------------------------------------
__global__ __launch_bounds__(256) void k_state(const float* __restrict__ u,
                                               const float* __restrict__ A_log,
                                               const float* __restrict__ B,
                                               const float* __restrict__ delta,
                                               float* __restrict__ out) {
    const int n = blockIdx.x & 63;
    const int b = blockIdx.x >> 6;
    const int tid = threadIdx.x;
    const float* ul = u + ((size_t)b * SEQL + (SEQL - 1)) * DMODEL;
    const float* Bn = B + (size_t)n * DMODEL;
    float dot = 0.f, dsum = 0.f;
    for (int dd = tid; dd < DMODEL; dd += 256) {
        dot = fmaf(Bn[dd], ul[dd], dot);
        dsum += delta[dd];
    }
#pragma unroll
    for (int off = 32; off > 0; off >>= 1) {
        dot  += __shfl_down(dot,  off, 64);
        dsum += __shfl_down(dsum, off, 64);
    }
    __shared__ float red[8];
    const int wave = tid >> 6, lane = tid & 63;
    if (lane == 0) { red[wave] = dot; red[4 + wave] = dsum; }
    __syncthreads();
    if (tid == 0) {
        dot  = red[0] + red[1] + red[2] + red[3];
        dsum = red[4] + red[5] + red[6] + red[7];
        const float dmean = dsum * (1.f / DMODEL);
        const float A = -expf(A_log[n]);
        const float Abar = expf(dmean * A);
        const float Asafe = A + (A >= 0.f ? 1e-8f : -1e-8f);
        out[blockIdx.x] = ((Abar - 1.f) / Asafe) * dot;
    }
}

extern "C" void kernel_launch(void* const* d_in, const int* in_sizes, int n_in,
                              void* d_out, int out_size, void* d_ws, size_t ws_size,
                              hipStream_t stream) {
    const float* u     = (const float*)d_in[0];
    const float* A_log = (const float*)d_in[1];
    const float* B     = (const float*)d_in[2];
    const float* C     = (const float*)d_in[3];
    const float* Dv    = (const float*)d_in[4];
    const float* delta = (const float*)d_in[5];
    const float* gamma = (const float*)d_in[6];
    const float* beta  = (const float*)d_in[7];
    const float* fal   = (const float*)d_in[8];
    const float* rw    = (const float*)d_in[9];

    float* y  = (float*)d_out;
    float* st = y + (size_t)BATCH * SEQL * DMODEL;
    u16* f    = (u16*)d_ws;

    int NCH = 32;
    while (NCH > 4 && (size_t)BATCH * NCH * NSTATE * DMODEL * sizeof(u16) > ws_size)
        NCH >>= 1;
    const int TCH = SEQL / NCH;
    const int nb = BATCH * 16 * NCH;

    const size_t f_bytes = (size_t)BATCH * NCH * NSTATE * DMODEL * sizeof(u16);
    const size_t z_bytes = (size_t)BATCH * SEQL * DMODEL * sizeof(u16);
    const bool zbf16 = (f_bytes + z_bytes) <= ws_size;
    void* zbuf = zbf16 ? (void*)((char*)d_ws + f_bytes) : (void*)y;

    hipLaunchKernelGGL(k_local, dim3(nb), dim3(256), 0, stream, u, A_log, delta, f, NCH, TCH);
    hipLaunchKernelGGL(k_pass2, dim3(BATCH * NSTATE * DMODEL / 256), dim3(256), 0, stream,
                       A_log, delta, f, NCH, TCH);
    if (zbf16) {
        hipLaunchKernelGGL((k_replay<true>), dim3(nb), dim3(256), 0, stream,
                           u, A_log, C, Dv, delta, f, fal, rw, zbuf, NCH, TCH);
        hipLaunchKernelGGL((k_ln<true>), dim3(BATCH * SEQL), dim3(256), 0, stream,
                           zbuf, y, gamma, beta);
    } else {
        hipLaunchKernelGGL((k_replay<false>), dim3(nb), dim3(256), 0, stream,
                           u, A_log, C, Dv, delta, f, fal, rw, zbuf, NCH, TCH);
        hipLaunchKernelGGL((k_ln<false>), dim3(BATCH * SEQL), dim3(256), 0, stream,
                           zbuf, y, gamma, beta);
    }
    hipLaunchKernelGGL(k_state, dim3(BATCH * NSTATE), dim3(256), 0, stream,
                       u, A_log, B, delta, st);
}